// Round 1
// baseline (496.895 us; speedup 1.0000x reference)
//
#include <hip/hip_runtime.h>
#include <cstddef>

#define N 1024
#define DN 128      // NODE_DIM
#define DE 16       // EDGE_DIM
#define DM 64       // MSG_DIM
#define TSTEPS 3
#define INDIM 272   // 2*DN + DE

// ---------------------------------------------------------------------------
// Kernel A: P[i, 0:64] = hi[i,:], P[i, 64:128] = hj[i,:], P[i, 128:512] = gh[i,:]+b_hh
// hi = H @ Wi.T (Wi = W1[:, 0:128]); hj = H @ Wj.T (Wj = W1[:, 128:256]); gh = H @ W_hh.T
// ---------------------------------------------------------------------------
__global__ __launch_bounds__(256) void kA(const float* __restrict__ H,
                                          const float* __restrict__ W1,
                                          const float* __restrict__ W_hh,
                                          const float* __restrict__ b_hh,
                                          float* __restrict__ P) {
  int i = blockIdx.x;
  int t = threadIdx.x;
  __shared__ float h[DN];
  if (t < DN) h[t] = H[i * DN + t];
  __syncthreads();
  for (int c = t; c < 512; c += 256) {
    const float* w;
    float acc;
    if (c < 64)       { w = W1 + c * INDIM;              acc = 0.f; }
    else if (c < 128) { w = W1 + (c - 64) * INDIM + 128; acc = 0.f; }
    else              { w = W_hh + (c - 128) * DN;       acc = b_hh[c - 128]; }
    const float4* w4 = (const float4*)w;
    #pragma unroll
    for (int k4 = 0; k4 < DN / 4; ++k4) {
      float4 wv = w4[k4];
      acc = fmaf(h[k4 * 4 + 0], wv.x, acc);
      acc = fmaf(h[k4 * 4 + 1], wv.y, acc);
      acc = fmaf(h[k4 * 4 + 2], wv.z, acc);
      acc = fmaf(h[k4 * 4 + 3], wv.w, acc);
    }
    P[i * 512 + c] = acc;
  }
}

// ---------------------------------------------------------------------------
// Kernel B: per row i:
//   S[i,m]  = sum_j A[i,j] * relu(hi[i,m] + hj[j,m] + Ep[i,j,m] + b1[m])
//   deg[i]  = sum_j A[i,j]
// Ep computed on the fly from E[i,j,:] @ We.T  (We = W1[:, 256:272]).
// Thread layout: mq = tid&15 (m-quad, m = 4*mq..4*mq+3), jj = tid>>4 (0..15).
// We rows for this thread's 4 m's held in 64 VGPRs; E loaded per-lane float4
// (16 lanes of one j share the address -> broadcast in L1).
// ---------------------------------------------------------------------------
__global__ __launch_bounds__(256) void kB(const float* __restrict__ P,
                                          const float* __restrict__ E,
                                          const float* __restrict__ W1,
                                          const float* __restrict__ b1,
                                          const int* __restrict__ A,
                                          float* __restrict__ S,
                                          float* __restrict__ deg) {
  int i  = blockIdx.x;
  int t  = threadIdx.x;
  int mq = t & 15;   // m-quad index
  int jj = t >> 4;   // 0..15

  // Load We[4m][16e] into registers.
  float we[4][16];
  #pragma unroll
  for (int mi = 0; mi < 4; ++mi) {
    const float4* wr4 = (const float4*)(W1 + (size_t)(mq * 4 + mi) * INDIM + 256);
    #pragma unroll
    for (int q = 0; q < 4; ++q) {
      float4 v = wr4[q];
      we[mi][q * 4 + 0] = v.x;
      we[mi][q * 4 + 1] = v.y;
      we[mi][q * 4 + 2] = v.z;
      we[mi][q * 4 + 3] = v.w;
    }
  }

  float hib[4];
  #pragma unroll
  for (int mi = 0; mi < 4; ++mi)
    hib[mi] = P[i * 512 + mq * 4 + mi] + b1[mq * 4 + mi];

  float s[4] = {0.f, 0.f, 0.f, 0.f};
  int degp = 0;

  const float* Erow = E + (size_t)i * N * DE;
  const int*   Arow = A + (size_t)i * N;

  for (int jt = 0; jt < N / 16; ++jt) {
    int j = jt * 16 + jj;

    const float4* e4 = (const float4*)(Erow + (size_t)j * DE);
    float4 q0 = e4[0], q1 = e4[1], q2 = e4[2], q3 = e4[3];
    float ev[16] = {q0.x, q0.y, q0.z, q0.w, q1.x, q1.y, q1.z, q1.w,
                    q2.x, q2.y, q2.z, q2.w, q3.x, q3.y, q3.z, q3.w};

    float4 hj4 = *(const float4*)(P + (size_t)j * 512 + 64 + mq * 4);
    int   a  = Arow[j];
    float af = (float)a;
    if (mq == 0) degp += a;

    float ep[4];
    #pragma unroll
    for (int mi = 0; mi < 4; ++mi) {
      float acc = 0.f;
      #pragma unroll
      for (int e = 0; e < 16; ++e) acc = fmaf(ev[e], we[mi][e], acc);
      ep[mi] = acc;
    }

    float pre0 = hib[0] + hj4.x + ep[0];
    float pre1 = hib[1] + hj4.y + ep[1];
    float pre2 = hib[2] + hj4.z + ep[2];
    float pre3 = hib[3] + hj4.w + ep[3];
    s[0] = fmaf(af, fmaxf(pre0, 0.f), s[0]);
    s[1] = fmaf(af, fmaxf(pre1, 0.f), s[1]);
    s[2] = fmaf(af, fmaxf(pre2, 0.f), s[2]);
    s[3] = fmaf(af, fmaxf(pre3, 0.f), s[3]);
  }

  __shared__ float red[16][DM];
  __shared__ float dred[16];
  *(float4*)&red[jj][mq * 4] = make_float4(s[0], s[1], s[2], s[3]);
  if (mq == 0) dred[jj] = (float)degp;
  __syncthreads();

  if (t < DM) {
    float acc = 0.f;
    #pragma unroll
    for (int r = 0; r < 16; ++r) acc += red[r][t];
    S[(size_t)i * DM + t] = acc;
  }
  if (t == 0) {
    float d = 0.f;
    #pragma unroll
    for (int r = 0; r < 16; ++r) d += dred[r];
    deg[i] = d;
  }
}

// ---------------------------------------------------------------------------
// Kernel C: per row i:
//   M  = S @ W2.T + deg*b2
//   gi = M @ W_ih.T + b_ih
//   GRU gates with gh (= P[i,128:512], b_hh already added), output new H row.
// ---------------------------------------------------------------------------
__global__ __launch_bounds__(256) void kC(const float* __restrict__ P,
                                          const float* __restrict__ S,
                                          const float* __restrict__ deg,
                                          const float* __restrict__ W2,
                                          const float* __restrict__ b2,
                                          const float* __restrict__ W_ih,
                                          const float* __restrict__ b_ih,
                                          const float* __restrict__ Hin,
                                          float* __restrict__ Hout) {
  int i = blockIdx.x;
  int t = threadIdx.x;
  __shared__ float sS[DM];
  __shared__ float sM[DM];
  __shared__ float sGi[384];

  if (t < DM) sS[t] = S[(size_t)i * DM + t];
  __syncthreads();

  if (t < DM) {
    float acc = deg[i] * b2[t];
    const float4* w4 = (const float4*)(W2 + (size_t)t * DM);
    #pragma unroll
    for (int k4 = 0; k4 < DM / 4; ++k4) {
      float4 wv = w4[k4];
      acc = fmaf(sS[k4 * 4 + 0], wv.x, acc);
      acc = fmaf(sS[k4 * 4 + 1], wv.y, acc);
      acc = fmaf(sS[k4 * 4 + 2], wv.z, acc);
      acc = fmaf(sS[k4 * 4 + 3], wv.w, acc);
    }
    sM[t] = acc;
  }
  __syncthreads();

  for (int c = t; c < 384; c += 256) {
    float acc = b_ih[c];
    const float4* w4 = (const float4*)(W_ih + (size_t)c * DM);
    #pragma unroll
    for (int k4 = 0; k4 < DM / 4; ++k4) {
      float4 wv = w4[k4];
      acc = fmaf(sM[k4 * 4 + 0], wv.x, acc);
      acc = fmaf(sM[k4 * 4 + 1], wv.y, acc);
      acc = fmaf(sM[k4 * 4 + 2], wv.z, acc);
      acc = fmaf(sM[k4 * 4 + 3], wv.w, acc);
    }
    sGi[c] = acc;
  }
  __syncthreads();

  if (t < DN) {
    float ghr = P[(size_t)i * 512 + 128 + t];
    float ghz = P[(size_t)i * 512 + 256 + t];
    float ghn = P[(size_t)i * 512 + 384 + t];
    float gir = sGi[t], giz = sGi[128 + t], gin = sGi[256 + t];
    float r = 1.f / (1.f + expf(-(gir + ghr)));
    float z = 1.f / (1.f + expf(-(giz + ghz)));
    float n = tanhf(gin + r * ghn);
    float h = Hin[(size_t)i * DN + t];
    Hout[(size_t)i * DN + t] = (1.f - z) * n + z * h;
  }
}

// ---------------------------------------------------------------------------
extern "C" void kernel_launch(void* const* d_in, const int* in_sizes, int n_in,
                              void* d_out, int out_size, void* d_ws, size_t ws_size,
                              hipStream_t stream) {
  const float* X    = (const float*)d_in[0];
  const int*   A    = (const int*)  d_in[1];
  const float* E    = (const float*)d_in[2];
  const float* W1   = (const float*)d_in[3];
  const float* b1   = (const float*)d_in[4];
  const float* W2   = (const float*)d_in[5];
  const float* b2   = (const float*)d_in[6];
  const float* W_ih = (const float*)d_in[7];
  const float* b_ih = (const float*)d_in[8];
  const float* W_hh = (const float*)d_in[9];
  const float* b_hh = (const float*)d_in[10];
  float* out = (float*)d_out;

  float* ws   = (float*)d_ws;
  float* Hbuf = ws;                    // N*DN     = 131072
  float* P    = Hbuf + N * DN;         // N*512    = 524288
  float* S    = P + N * 512;           // N*DM     = 65536
  float* deg  = S + N * DM;            // N        = 1024

  hipMemcpyAsync(Hbuf, X, (size_t)N * DN * sizeof(float),
                 hipMemcpyDeviceToDevice, stream);

  for (int step = 0; step < TSTEPS; ++step) {
    kA<<<N, 256, 0, stream>>>(Hbuf, W1, W_hh, b_hh, P);
    kB<<<N, 256, 0, stream>>>(P, E, W1, b1, A, S, deg);
    float* Hout = (step == TSTEPS - 1) ? out : Hbuf;
    kC<<<N, 256, 0, stream>>>(P, S, deg, W2, b2, W_ih, b_ih, Hbuf, Hout);
  }
}